// Round 1
// baseline (575.335 us; speedup 1.0000x reference)
//
#include <hip/hip_runtime.h>
#include <stdint.h>

#define BATCH 32768
#define NN    2500
#define NPAD  2560
#define DIM   256

#define BM 128
#define BN 128
#define BKP 32   // pipelined K-step (double-buffered)

typedef __attribute__((ext_vector_type(8))) short short8;
typedef __attribute__((ext_vector_type(4))) float float4_;

__device__ __forceinline__ unsigned short f2bf(float f) {
  union { float f; uint32_t u; } v; v.f = f;
  uint32_t u = v.u;
  return (unsigned short)((u + 0x7FFFu + ((u >> 16) & 1u)) >> 16);
}

__device__ __forceinline__ void gload_lds16(const void* g, void* lds) {
  __builtin_amdgcn_global_load_lds(
      (const __attribute__((address_space(1))) unsigned int*)g,
      (__attribute__((address_space(3))) unsigned int*)lds, 16, 0, 0);
}

// ---------------- prep: fp32 -> bf16 copy + exact fp32 row norm ----------------
// Single launch covering X rows [0,BATCH) then W rows [BATCH, BATCH+NPAD).
// Xb/Wb are contiguous in ws, as are xsq/wsq, so one output pointer each.
__global__ void prep_rows2(const float* __restrict__ xin, const float* __restrict__ win_,
                           unsigned short* __restrict__ outb, float* __restrict__ sq) {
  int row  = blockIdx.x * 4 + (threadIdx.x >> 6);
  int lane = threadIdx.x & 63;
  float4 v = make_float4(0.f, 0.f, 0.f, 0.f);
  if (row < BATCH) {
    v = ((const float4*)(xin + (size_t)row * DIM))[lane];
  } else if (row - BATCH < NN) {
    v = ((const float4*)(win_ + (size_t)(row - BATCH) * DIM))[lane];
  }
  float s = v.x * v.x + v.y * v.y + v.z * v.z + v.w * v.w;
  *(ushort4*)(outb + (size_t)row * DIM + lane * 4) =
      make_ushort4(f2bf(v.x), f2bf(v.y), f2bf(v.z), f2bf(v.w));
  for (int off = 32; off > 0; off >>= 1) s += __shfl_down(s, off, 64);
  if (lane == 0) sq[row] = s;
}

// ---------------- main GEMM: 2-phase pipelined, dbuf BK=32, XCD-chunked grid ----------------
// LDS tile: 128 rows x 32 bf16 (64 B rows), 16B chunks; physical chunk(r, pc)
// holds logical chunk pc ^ (r&3). Fragment ds_read_b128: offsets mod 128 cover
// all 8 16B slots -> minimum 8 bank-accesses/bank = conflict-free.
// Schedule (T3 minimal 2-phase): stage(next) -> ds_read+MFMA(cur) -> sync.
// The vmcnt(0) inside __syncthreads drains loads issued ~1000 cy earlier.
__global__ __launch_bounds__(256, 4)
void cdist_gemm_bf16(const unsigned short* __restrict__ Xb,
                     const unsigned short* __restrict__ Wb,
                     const float* __restrict__ xsq, const float* __restrict__ wsq,
                     float* __restrict__ out) {
  __shared__ __align__(16) unsigned short As[2][BM * BKP];   // 2 x 8 KB
  __shared__ __align__(16) unsigned short Bs[2][BN * BKP];   // 2 x 8 KB

  const int tid  = threadIdx.x;
  const int lane = tid & 63;
  const int wave = tid >> 6;

  // XCD-chunked mapping: 5120 blocks = 8 XCDs x 640; per XCD 32 M-tiles x 20
  // N-tiles, N inner -> A-tile (64 KB) reused from local L2 across all 20 uses,
  // W (1.31 MB bf16) stays L2-resident per XCD.
  const int bid = blockIdx.x;
  const int loc = bid >> 3;                  // 0..639
  const int mt  = (bid & 7) * 32 + loc / 20; // 0..255
  const int nt  = loc % 20;                  // 0..19
  const int m0  = mt * BM;
  const int n0  = nt * BN;

  const int wr = wave >> 1;
  const int wc = wave & 1;

  float4_ acc[4][4] = {};

  // staging: window = 16 rows x 32 cols = 1 KB; wave w stages windows {2w, 2w+1}
  // of both A and B. lane -> (lr = row in window, cc = 16B chunk), source chunk
  // pre-swizzled so LDS (linear dest) ends up swizzled.
  const int lr  = lane >> 2;          // 0..15
  const int cc  = lane & 3;           // 0..3
  const int csw = cc ^ (lr & 3);      // swizzled source chunk

  const unsigned short* gA = Xb + (size_t)(m0 + wave * 32 + lr) * DIM + csw * 8;
  const unsigned short* gB = Wb + (size_t)(n0 + wave * 32 + lr) * DIM + csw * 8;

  const int q = lane >> 4;            // k-chunk 0..3 (k = q*8..q*8+7)
  const int i = lane & 15;            // row-in-fragment

#define STAGE(bufi, kc)                                                        \
  {                                                                            \
    _Pragma("unroll")                                                          \
    for (int t = 0; t < 2; ++t) {                                              \
      gload_lds16(gA + (size_t)(t * 16) * DIM + (kc), &As[bufi][(wave * 2 + t) * 512]); \
      gload_lds16(gB + (size_t)(t * 16) * DIM + (kc), &Bs[bufi][(wave * 2 + t) * 512]); \
    }                                                                          \
  }

  STAGE(0, 0);
  __syncthreads();

#pragma unroll
  for (int it = 0; it < 8; ++it) {
    const int buf = it & 1;
    if (it < 7) STAGE(buf ^ 1, (it + 1) * BKP);

    short8 a[4], b[4];
#pragma unroll
    for (int t = 0; t < 4; ++t) {
      int r  = t * 16 + i;            // r&3 == i&3 (base multiple of 16)
      int pc = q ^ (i & 3);
      a[t] = *(const short8*)&As[buf][(wr * 64 + r) * BKP + pc * 8];
      b[t] = *(const short8*)&Bs[buf][(wc * 64 + r) * BKP + pc * 8];
    }
#pragma unroll
    for (int ti = 0; ti < 4; ++ti)
#pragma unroll
      for (int tj = 0; tj < 4; ++tj)
        acc[ti][tj] = __builtin_amdgcn_mfma_f32_16x16x32_bf16(
            a[ti], b[tj], acc[ti][tj], 0, 0, 0);

    __syncthreads();
  }
#undef STAGE

  // epilogue: d = sqrt(max(xsq + wsq - 2*cross, 0))
  // C/D layout: col = lane&15, row = (lane>>4)*4 + reg  [m89/m91]
  // nontemporal: output is write-once; keep it out of the L2 holding A/B.
#pragma unroll
  for (int ti = 0; ti < 4; ++ti) {
    int grow_base = m0 + wr * 64 + ti * 16 + q * 4;
#pragma unroll
    for (int tj = 0; tj < 4; ++tj) {
      int gcol = n0 + wc * 64 + tj * 16 + i;
      if (gcol < NN) {
        float wn = wsq[gcol];
#pragma unroll
        for (int r = 0; r < 4; ++r) {
          int grow = grow_base + r;
          float d2 = xsq[grow] + wn - 2.0f * acc[ti][tj][r];
          __builtin_nontemporal_store(sqrtf(fmaxf(d2, 0.f)),
                                      &out[(size_t)grow * NN + gcol]);
        }
      }
    }
  }
}

// ---------------- fallback path (ws too small): round-1 kernels ----------------
#define LDA 72
#define BKF 64
__global__ void row_sq_norm(const float* __restrict__ in, float* __restrict__ out,
                            int nrows, int nvalid) {
  int row  = blockIdx.x * 4 + (threadIdx.x >> 6);
  int lane = threadIdx.x & 63;
  if (row >= nrows) return;
  float s = 0.f;
  if (row < nvalid) {
    float4 v = ((const float4*)(in + (size_t)row * DIM))[lane];
    s = v.x * v.x + v.y * v.y + v.z * v.z + v.w * v.w;
  }
  for (int off = 32; off > 0; off >>= 1) s += __shfl_down(s, off, 64);
  if (lane == 0) out[row] = s;
}

__global__ __launch_bounds__(256, 2)
void cdist_gemm_f32(const float* __restrict__ X, const float* __restrict__ W,
                    const float* __restrict__ xsq, const float* __restrict__ wsq,
                    float* __restrict__ out) {
  __shared__ __align__(16) unsigned short As[BM * LDA];
  __shared__ __align__(16) unsigned short Bs[BN * LDA];
  const int tid = threadIdx.x, lane = tid & 63, wave = tid >> 6;
  const int m0 = blockIdx.x * BM, n0 = blockIdx.y * BN;
  const int wr = wave >> 1, wc = wave & 1;
  float4_ acc[4][4] = {};
  const int s_col4 = tid & 15, s_row0 = tid >> 4;
  for (int kc = 0; kc < DIM; kc += BKF) {
#pragma unroll
    for (int j = 0; j < 8; ++j) {
      int r = s_row0 + 16 * j;
      float4 v = *(const float4*)(X + (size_t)(m0 + r) * DIM + kc + s_col4 * 4);
      *(ushort4*)&As[r * LDA + s_col4 * 4] =
          make_ushort4(f2bf(v.x), f2bf(v.y), f2bf(v.z), f2bf(v.w));
    }
#pragma unroll
    for (int j = 0; j < 8; ++j) {
      int r = s_row0 + 16 * j, n = n0 + r;
      float4 v = make_float4(0.f, 0.f, 0.f, 0.f);
      if (n < NN) v = *(const float4*)(W + (size_t)n * DIM + kc + s_col4 * 4);
      *(ushort4*)&Bs[r * LDA + s_col4 * 4] =
          make_ushort4(f2bf(v.x), f2bf(v.y), f2bf(v.z), f2bf(v.w));
    }
    __syncthreads();
    const int q = lane >> 4, i = lane & 15;
#pragma unroll
    for (int ks = 0; ks < BKF; ks += 32) {
      short8 a[4], b[4];
#pragma unroll
      for (int t = 0; t < 4; ++t) {
        a[t] = *(const short8*)&As[(wr * 64 + t * 16 + i) * LDA + ks + q * 8];
        b[t] = *(const short8*)&Bs[(wc * 64 + t * 16 + i) * LDA + ks + q * 8];
      }
#pragma unroll
      for (int ti = 0; ti < 4; ++ti)
#pragma unroll
        for (int tj = 0; tj < 4; ++tj)
          acc[ti][tj] = __builtin_amdgcn_mfma_f32_16x16x32_bf16(
              a[ti], b[tj], acc[ti][tj], 0, 0, 0);
    }
    __syncthreads();
  }
  const int q = lane >> 4, i = lane & 15;
#pragma unroll
  for (int ti = 0; ti < 4; ++ti) {
    int grow_base = m0 + wr * 64 + ti * 16 + q * 4;
#pragma unroll
    for (int tj = 0; tj < 4; ++tj) {
      int gcol = n0 + wc * 64 + tj * 16 + i;
      if (gcol < NN) {
        float wn = wsq[gcol];
#pragma unroll
        for (int r = 0; r < 4; ++r) {
          int grow = grow_base + r;
          float d2 = xsq[grow] + wn - 2.0f * acc[ti][tj][r];
          out[(size_t)grow * NN + gcol] = sqrtf(fmaxf(d2, 0.f));
        }
      }
    }
  }
}

extern "C" void kernel_launch(void* const* d_in, const int* in_sizes, int n_in,
                              void* d_out, int out_size, void* d_ws, size_t ws_size,
                              hipStream_t stream) {
  const float* x = (const float*)d_in[0];
  const float* w = (const float*)d_in[1];

  const size_t xb_elems = (size_t)BATCH * DIM;          // bf16
  const size_t wb_elems = (size_t)NPAD * DIM;           // bf16
  const size_t need = xb_elems * 2 + wb_elems * 2 + (size_t)BATCH * 4 + (size_t)NPAD * 4;

  if (ws_size >= need) {
    unsigned short* Xb = (unsigned short*)d_ws;
    unsigned short* Wb = Xb + xb_elems;
    float* xsq = (float*)(Wb + wb_elems);
    float* wsq = xsq + BATCH;

    // one prep launch: X rows then W rows (outputs are contiguous in ws)
    prep_rows2<<<(BATCH + NPAD) / 4, 256, 0, stream>>>(x, w, Xb, xsq);

    cdist_gemm_bf16<<<dim3((BATCH / BM) * (NPAD / BN)), 256, 0, stream>>>(
        Xb, Wb, xsq, wsq, (float*)d_out);
  } else {
    float* xsq = (float*)d_ws;
    float* wsq = xsq + BATCH;
    row_sq_norm<<<BATCH / 4, 256, 0, stream>>>(x, xsq, BATCH, BATCH);
    row_sq_norm<<<NPAD / 4, 256, 0, stream>>>(w, wsq, NPAD, NN);
    dim3 grid(BATCH / BM, NPAD / BN);
    cdist_gemm_f32<<<grid, 256, 0, stream>>>(x, w, xsq, wsq, (float*)d_out);
  }
}

// Round 2
// 464.072 us; speedup vs baseline: 1.2398x; 1.2398x over previous
//
#include <hip/hip_runtime.h>
#include <stdint.h>

#define BATCH 32768
#define NN    2500
#define NPAD  2560
#define DIM   256

#define BM 128
#define BN 128

typedef __attribute__((ext_vector_type(8))) short short8;
typedef __attribute__((ext_vector_type(4))) float float4_;

__device__ __forceinline__ unsigned short f2bf(float f) {
  union { float f; uint32_t u; } v; v.f = f;
  uint32_t u = v.u;
  return (unsigned short)((u + 0x7FFFu + ((u >> 16) & 1u)) >> 16);
}

__device__ __forceinline__ void gload_lds16(const void* g, void* lds) {
  __builtin_amdgcn_global_load_lds(
      (const __attribute__((address_space(1))) unsigned int*)g,
      (__attribute__((address_space(3))) unsigned int*)lds, 16, 0, 0);
}

// ---------------- prep: fp32 -> bf16 copy + exact fp32 row norm ----------------
__global__ void prep_rows2(const float* __restrict__ xin, const float* __restrict__ win_,
                           unsigned short* __restrict__ outb, float* __restrict__ sq) {
  int row  = blockIdx.x * 4 + (threadIdx.x >> 6);
  int lane = threadIdx.x & 63;
  float4 v = make_float4(0.f, 0.f, 0.f, 0.f);
  if (row < BATCH) {
    v = ((const float4*)(xin + (size_t)row * DIM))[lane];
  } else if (row - BATCH < NN) {
    v = ((const float4*)(win_ + (size_t)(row - BATCH) * DIM))[lane];
  }
  float s = v.x * v.x + v.y * v.y + v.z * v.z + v.w * v.w;
  *(ushort4*)(outb + (size_t)row * DIM + lane * 4) =
      make_ushort4(f2bf(v.x), f2bf(v.y), f2bf(v.z), f2bf(v.w));
  for (int off = 32; off > 0; off >>= 1) s += __shfl_down(s, off, 64);
  if (lane == 0) sq[row] = s;
}

// ---------------- main GEMM: B-panel resident in LDS, barrier-free K-loop ----------------
// K=256 is tiny: whole B panel (128 x 256 bf16 = 64 KB) staged to LDS ONCE
// (single __syncthreads in the kernel), A streamed global->reg with a depth-2
// register double buffer. No per-K-step barriers, no vmcnt(0) drains in the loop.
// LDS swizzle: physical 16B-chunk pc of row r holds logical chunk pc ^ (r&7);
// fragment read slot-in-128B = ((ks*4+q)&7) ^ (i&7): lanes 0..7 hit 8 distinct
// slots -> conflict-free ds_read_b128 (the round-1 4-chunk variant was 2-way).
// 8 waves (4x2): wave = 32 rows x 64 cols, acc[2][4].
__global__ __launch_bounds__(512, 4)
void cdist_gemm_bf16(const unsigned short* __restrict__ Xb,
                     const unsigned short* __restrict__ Wb,
                     const float* __restrict__ xsq, const float* __restrict__ wsq,
                     float* __restrict__ out) {
  __shared__ __align__(16) unsigned short Bs[BN * DIM];   // 64 KB

  const int tid  = threadIdx.x;
  const int lane = tid & 63;
  const int wave = tid >> 6;                 // 0..7

  // XCD-chunked mapping: 5120 blocks = 8 XCDs x 640; per XCD 32 M-tiles x 20
  // N-tiles, N inner -> X tile set (2 MB) + W (1.31 MB) L2-resident per XCD.
  const int bid = blockIdx.x;
  const int loc = bid >> 3;                  // 0..639
  const int mt  = (bid & 7) * 32 + loc / 20; // 0..255
  const int nt  = loc % 20;                  // 0..19
  const int m0  = mt * BM;
  const int n0  = nt * BN;

  const int wr = wave >> 1;                  // 0..3  (32-row slice)
  const int wc = wave & 1;                   // 0..1  (64-col slice)
  const int q  = lane >> 4;                  // k-chunk 0..3
  const int i  = lane & 15;

  // ---- stage whole B panel once: 4096 16B chunks, linear LDS dest,
  //      pre-swizzled global source (chunk lc = pc ^ (row&7)) ----
#pragma unroll
  for (int j = 0; j < 8; ++j) {
    int c   = j * 512 + tid;                 // chunk id 0..4095
    int row = c >> 5;                        // 32 chunks per 512B row
    int pc  = c & 31;
    int lc  = pc ^ (row & 7);
    gload_lds16(Wb + (size_t)(n0 + row) * DIM + lc * 8, &Bs[c * 8]);
  }

  // per-lane A base: row (m0 + wr*32 + i), k-chunk q
  const unsigned short* gA = Xb + (size_t)(m0 + wr * 32 + i) * DIM + q * 8;

  // depth-2 register prefetch of A fragments (issued before the barrier;
  // they touch only global memory, independent of the LDS stage)
  short8 a0_0 = *(const short8*)(gA);
  short8 a0_1 = *(const short8*)(gA + 16 * DIM);
  short8 a1_0 = *(const short8*)(gA + 32);
  short8 a1_1 = *(const short8*)(gA + 16 * DIM + 32);

  float4_ acc[2][4] = {};

  __syncthreads();   // the ONLY barrier: B panel resident from here on

#pragma unroll
  for (int ks = 0; ks < 8; ++ks) {
    short8 a2_0, a2_1;
    if (ks < 6) {
      a2_0 = *(const short8*)(gA + (ks + 2) * 32);
      a2_1 = *(const short8*)(gA + 16 * DIM + (ks + 2) * 32);
    }
    short8 b[4];
#pragma unroll
    for (int tj = 0; tj < 4; ++tj) {
      int row = wc * 64 + tj * 16 + i;
      int pc  = (ks * 4 + q) ^ (i & 7);
      b[tj] = *(const short8*)&Bs[(row << 8) + (pc << 3)];
    }
#pragma unroll
    for (int tj = 0; tj < 4; ++tj) {
      acc[0][tj] = __builtin_amdgcn_mfma_f32_16x16x32_bf16(a0_0, b[tj], acc[0][tj], 0, 0, 0);
      acc[1][tj] = __builtin_amdgcn_mfma_f32_16x16x32_bf16(a0_1, b[tj], acc[1][tj], 0, 0, 0);
    }
    if (ks < 7) { a0_0 = a1_0; a0_1 = a1_1; }
    if (ks < 6) { a1_0 = a2_0; a1_1 = a2_1; }
  }

  // epilogue: d = sqrt(max(xsq + wsq - 2*cross, 0))
  // C/D layout: col = lane&15, row = (lane>>4)*4 + reg  [m89/m91]
  // plain stores: straddling 128B lines coalesce in L2 (NT stores cost +49%
  // WRITE_SIZE in round 1 — rows are 10000B, 16B-misaligned vs lines).
#pragma unroll
  for (int ti = 0; ti < 2; ++ti) {
    int grow_base = m0 + wr * 32 + ti * 16 + q * 4;
#pragma unroll
    for (int tj = 0; tj < 4; ++tj) {
      int gcol = n0 + wc * 64 + tj * 16 + i;
      if (gcol < NN) {
        float wn = wsq[gcol];
#pragma unroll
        for (int r = 0; r < 4; ++r) {
          int grow = grow_base + r;
          float d2 = xsq[grow] + wn - 2.0f * acc[ti][tj][r];
          out[(size_t)grow * NN + gcol] = sqrtf(fmaxf(d2, 0.f));
        }
      }
    }
  }
}

// ---------------- fallback path (ws too small): round-1 kernels ----------------
#define LDA 72
#define BKF 64
__global__ void row_sq_norm(const float* __restrict__ in, float* __restrict__ out,
                            int nrows, int nvalid) {
  int row  = blockIdx.x * 4 + (threadIdx.x >> 6);
  int lane = threadIdx.x & 63;
  if (row >= nrows) return;
  float s = 0.f;
  if (row < nvalid) {
    float4 v = ((const float4*)(in + (size_t)row * DIM))[lane];
    s = v.x * v.x + v.y * v.y + v.z * v.z + v.w * v.w;
  }
  for (int off = 32; off > 0; off >>= 1) s += __shfl_down(s, off, 64);
  if (lane == 0) out[row] = s;
}

__global__ __launch_bounds__(256, 2)
void cdist_gemm_f32(const float* __restrict__ X, const float* __restrict__ W,
                    const float* __restrict__ xsq, const float* __restrict__ wsq,
                    float* __restrict__ out) {
  __shared__ __align__(16) unsigned short As[BM * LDA];
  __shared__ __align__(16) unsigned short Bs2[BN * LDA];
  const int tid = threadIdx.x, lane = tid & 63, wave = tid >> 6;
  const int m0 = blockIdx.x * BM, n0 = blockIdx.y * BN;
  const int wr = wave >> 1, wc = wave & 1;
  float4_ acc[4][4] = {};
  const int s_col4 = tid & 15, s_row0 = tid >> 4;
  for (int kc = 0; kc < DIM; kc += BKF) {
#pragma unroll
    for (int j = 0; j < 8; ++j) {
      int r = s_row0 + 16 * j;
      float4 v = *(const float4*)(X + (size_t)(m0 + r) * DIM + kc + s_col4 * 4);
      *(ushort4*)&As[r * LDA + s_col4 * 4] =
          make_ushort4(f2bf(v.x), f2bf(v.y), f2bf(v.z), f2bf(v.w));
    }
#pragma unroll
    for (int j = 0; j < 8; ++j) {
      int r = s_row0 + 16 * j, n = n0 + r;
      float4 v = make_float4(0.f, 0.f, 0.f, 0.f);
      if (n < NN) v = *(const float4*)(W + (size_t)n * DIM + kc + s_col4 * 4);
      *(ushort4*)&Bs2[r * LDA + s_col4 * 4] =
          make_ushort4(f2bf(v.x), f2bf(v.y), f2bf(v.z), f2bf(v.w));
    }
    __syncthreads();
    const int q = lane >> 4, i = lane & 15;
#pragma unroll
    for (int ks = 0; ks < BKF; ks += 32) {
      short8 a[4], b[4];
#pragma unroll
      for (int t = 0; t < 4; ++t) {
        a[t] = *(const short8*)&As[(wr * 64 + t * 16 + i) * LDA + ks + q * 8];
        b[t] = *(const short8*)&Bs2[(wc * 64 + t * 16 + i) * LDA + ks + q * 8];
      }
#pragma unroll
      for (int ti = 0; ti < 4; ++ti)
#pragma unroll
        for (int tj = 0; tj < 4; ++tj)
          acc[ti][tj] = __builtin_amdgcn_mfma_f32_16x16x32_bf16(
              a[ti], b[tj], acc[ti][tj], 0, 0, 0);
    }
    __syncthreads();
  }
  const int q = lane >> 4, i = lane & 15;
#pragma unroll
  for (int ti = 0; ti < 4; ++ti) {
    int grow_base = m0 + wr * 64 + ti * 16 + q * 4;
#pragma unroll
    for (int tj = 0; tj < 4; ++tj) {
      int gcol = n0 + wc * 64 + tj * 16 + i;
      if (gcol < NN) {
        float wn = wsq[gcol];
#pragma unroll
        for (int r = 0; r < 4; ++r) {
          int grow = grow_base + r;
          float d2 = xsq[grow] + wn - 2.0f * acc[ti][tj][r];
          out[(size_t)grow * NN + gcol] = sqrtf(fmaxf(d2, 0.f));
        }
      }
    }
  }
}

extern "C" void kernel_launch(void* const* d_in, const int* in_sizes, int n_in,
                              void* d_out, int out_size, void* d_ws, size_t ws_size,
                              hipStream_t stream) {
  const float* x = (const float*)d_in[0];
  const float* w = (const float*)d_in[1];

  const size_t xb_elems = (size_t)BATCH * DIM;          // bf16
  const size_t wb_elems = (size_t)NPAD * DIM;           // bf16
  const size_t need = xb_elems * 2 + wb_elems * 2 + (size_t)BATCH * 4 + (size_t)NPAD * 4;

  if (ws_size >= need) {
    unsigned short* Xb = (unsigned short*)d_ws;
    unsigned short* Wb = Xb + xb_elems;
    float* xsq = (float*)(Wb + wb_elems);
    float* wsq = xsq + BATCH;

    prep_rows2<<<(BATCH + NPAD) / 4, 256, 0, stream>>>(x, w, Xb, xsq);

    cdist_gemm_bf16<<<dim3((BATCH / BM) * (NPAD / BN)), 512, 0, stream>>>(
        Xb, Wb, xsq, wsq, (float*)d_out);
  } else {
    float* xsq = (float*)d_ws;
    float* wsq = xsq + BATCH;
    row_sq_norm<<<BATCH / 4, 256, 0, stream>>>(x, xsq, BATCH, BATCH);
    row_sq_norm<<<NPAD / 4, 256, 0, stream>>>(w, wsq, NPAD, NN);
    dim3 grid(BATCH / BM, NPAD / BN);
    cdist_gemm_f32<<<grid, 256, 0, stream>>>(x, w, xsq, wsq, (float*)d_out);
  }
}